// Round 11
// baseline (62.449 us; speedup 1.0000x reference)
//
#include <hip/hip_runtime.h>
#include <math.h>

// PatchNorm forward (training-mode Welford update + normalize), 3 kernels:
//   k_pf:   pf16[i] = cell id (0xFFFF = padded) + zero cnt[HW]
//   k_fill: bucket fill: slot = atomicAdd(&cnt[g]) -> list[g*128+slot] = i
//           (int atomics over 1024 counters: measured cheap in round 3)
//   k_cell: one block per cell, NO scan phase (list precomputed), 8 blocks/CU
//           (launch_bounds(256,8), LDS ~11 KB): gather rows (4-deep batches)
//           -> closed-form stats in LDS -> normalize same rows (L2/L3-hot).
// Rounds 6-10 lesson: per-wave MLP fixes (reg batching, sched_barrier pin,
// async global_load_lds) all landed at ~2.6 TB/s; occupancy was pinned at
// 4 blocks/CU the whole time. This round doubles TLP (8 blocks/CU) and
// removes the per-block redundant 32768-token scan (~5us VALU/SIMD).
//
// Closed-form per-cell moments (n_g uniform within a cell):
//   mean_new = mo + (S1 - cnt*mo)/n_g                 S1 = sum_valid xbar
//   m2_new   = m2 + S2 - (mo+mn)*S1 + cnt*mo*mn       S2 = sum_valid xbar^2

#define EPSF 1e-6f

static constexpr int W_GRID = 32;    // grid width (pf = pos_h*W + pos_w)
static constexpr int P2     = 256;   // patch_res^2
static constexpr int P4     = 64;    // P2/4
static constexpr int D4     = 192;   // D/4 float4 chunks per token
static constexpr int HW     = 1024;  // grid cells
static constexpr int NTOK   = 32768; // tokens
static constexpr int MAXTOK = 128;   // bucket capacity (E[cnt]=28.8, max~50)
static constexpr int SLICE  = NTOK / HW; // 32 tokens/block for pad-zeroing

// ---- kernel 1: pack cell ids + zero bucket counters -------------------------
__global__ void k_pf(const int* __restrict__ pos_h,
                     const int* __restrict__ pos_w,
                     const int* __restrict__ mask,
                     unsigned short* __restrict__ pf16,
                     int* __restrict__ cnt) {
    const int i = blockIdx.x * blockDim.x + threadIdx.x;
    if (i < HW) cnt[i] = 0;
    if (i >= NTOK) return;
    const int valid = (mask[i] == 0);
    pf16[i] = valid ? (unsigned short)(pos_h[i] * W_GRID + pos_w[i])
                    : (unsigned short)0xFFFF;
}

// ---- kernel 2: bucket fill ---------------------------------------------------
__global__ void k_fill(const unsigned short* __restrict__ pf16,
                       int* __restrict__ cnt,
                       int* __restrict__ list) {
    const int i = blockIdx.x * blockDim.x + threadIdx.x;
    if (i >= NTOK) return;
    const int g = pf16[i];
    if (g == 0xFFFF) return;
    const int slot = atomicAdd(&cnt[g], 1);
    if (slot < MAXTOK) list[g * MAXTOK + slot] = i;
}

// ---- kernel 3: fused per-cell moments + stats + normalize -------------------
__global__ void __launch_bounds__(256, 8)
k_cell(const float4* __restrict__ patches4,
       const unsigned short* __restrict__ pf16,
       const int* __restrict__ cnt,
       const int* __restrict__ list_g,
       const float* __restrict__ n_old,
       const float* __restrict__ mean_old,
       const float* __restrict__ m2_old,
       float4* __restrict__ out4) {
    const int g    = blockIdx.x;
    const int tid  = threadIdx.x;
    const int wave = tid >> 6;
    const int lane = tid & 63;

    __shared__ int            list[MAXTOK];
    __shared__ unsigned short s_slice[SLICE];
    __shared__ float4         l14[4][64];
    __shared__ float4         l24[4][64];
    __shared__ float4         mn_s[P4];
    __shared__ float4         is_s[P4];

    const int c = min(cnt[g], MAXTOK);
    if (tid < c) list[tid] = list_g[g * MAXTOK + tid];
    if (tid < SLICE) s_slice[tid] = pf16[g * SLICE + tid];
    __syncthreads();

    // ---- pad-zeroing for this block's 32-token slice -----------------------
#pragma unroll
    for (int t = 0; t < SLICE; ++t) {
        if (s_slice[t] == 0xFFFF) {
            const int i = g * SLICE + t;
            if (tid < D4)
                out4[(size_t)i * D4 + tid] = make_float4(0.f, 0.f, 0.f, 0.f);
        }
    }

    // ---- gather: S1/S2 moments, predicated 4-deep batches -------------------
    float4 s1 = make_float4(0.f, 0.f, 0.f, 0.f);
    float4 s2 = make_float4(0.f, 0.f, 0.f, 0.f);
    for (int k = wave; k < c; k += 16) {
        int   idx[4];
        float wf[4];
#pragma unroll
        for (int j = 0; j < 4; ++j) {
            const int  kk  = k + 4 * j;
            const bool val = (kk < c);
            wf[j]  = val ? 1.0f : 0.0f;
            idx[j] = list[val ? kk : k];      // k itself is always < c
        }
        float4 A[4], B[4], Dd[4];
#pragma unroll
        for (int j = 0; j < 4; ++j) {
            const float4* tp = patches4 + (size_t)idx[j] * D4 + lane;
            A[j]  = tp[0];
            B[j]  = tp[P4];
            Dd[j] = tp[2 * P4];
        }
#pragma unroll
        for (int j = 0; j < 4; ++j) {
            const float f = (1.0f / 3.0f) * wf[j];
            float4 xb;
            xb.x = (A[j].x + B[j].x + Dd[j].x) * f;
            xb.y = (A[j].y + B[j].y + Dd[j].y) * f;
            xb.z = (A[j].z + B[j].z + Dd[j].z) * f;
            xb.w = (A[j].w + B[j].w + Dd[j].w) * f;
            s1.x += xb.x; s1.y += xb.y; s1.z += xb.z; s1.w += xb.w;
            s2.x += xb.x * xb.x; s2.y += xb.y * xb.y;
            s2.z += xb.z * xb.z; s2.w += xb.w * xb.w;   // wf^2 == wf
        }
    }

    // ---- cross-wave reduce + closed-form stats (tid = p index) --------------
    l14[wave][lane] = s1;
    l24[wave][lane] = s2;
    __syncthreads();

    {
        const float* l1f = (const float*)l14;
        const float* l2f = (const float*)l24;
        const float S1 = l1f[tid] + l1f[256 + tid] + l1f[512 + tid] + l1f[768 + tid];
        const float S2 = l2f[tid] + l2f[256 + tid] + l2f[512 + tid] + l2f[768 + tid];

        const float cntf = (float)c;
        const float nn   = n_old[g] + cntf;
        const float ng   = fmaxf(nn, 1.0f);
        const int   j    = g * P2 + tid;
        const float mo   = mean_old[j];
        const float mn   = mo + (S1 - cntf * mo) / ng;
        const float m2n  = m2_old[j] + (S2 - (mo + mn) * S1 + cntf * mo * mn);
        const float var  = (nn < 2.0f) ? 1.0f : (m2n / ng);
        ((float*)mn_s)[tid] = mn;
        ((float*)is_s)[tid] = 1.0f / (sqrtf(var) + EPSF);
    }
    __syncthreads();

    // ---- normalize the same rows (L2/L3-hot re-read), 4-deep batches --------
    const float4 m4 = mn_s[lane];
    const float4 s4 = is_s[lane];
    for (int k = wave; k < c; k += 16) {
        int  idx[4];
        bool val[4];
#pragma unroll
        for (int j = 0; j < 4; ++j) {
            const int kk = k + 4 * j;
            val[j] = (kk < c);                // wave-uniform predicate
            idx[j] = list[val[j] ? kk : k];
        }
        float4 X[12];
#pragma unroll
        for (int j = 0; j < 4; ++j) {
            const float4* tp = patches4 + (size_t)idx[j] * D4 + lane;
            X[3 * j]     = tp[0];
            X[3 * j + 1] = tp[P4];
            X[3 * j + 2] = tp[2 * P4];
        }
#pragma unroll
        for (int j = 0; j < 4; ++j) {
            if (val[j]) {                     // uniform branch: masked stores
                float4* op = out4 + (size_t)idx[j] * D4 + lane;
                float4 r;
                r.x = (X[3 * j].x - m4.x) * s4.x;
                r.y = (X[3 * j].y - m4.y) * s4.y;
                r.z = (X[3 * j].z - m4.z) * s4.z;
                r.w = (X[3 * j].w - m4.w) * s4.w;
                op[0] = r;
                r.x = (X[3 * j + 1].x - m4.x) * s4.x;
                r.y = (X[3 * j + 1].y - m4.y) * s4.y;
                r.z = (X[3 * j + 1].z - m4.z) * s4.z;
                r.w = (X[3 * j + 1].w - m4.w) * s4.w;
                op[P4] = r;
                r.x = (X[3 * j + 2].x - m4.x) * s4.x;
                r.y = (X[3 * j + 2].y - m4.y) * s4.y;
                r.z = (X[3 * j + 2].z - m4.z) * s4.z;
                r.w = (X[3 * j + 2].w - m4.w) * s4.w;
                op[2 * P4] = r;
            }
        }
    }
}

extern "C" void kernel_launch(void* const* d_in, const int* in_sizes, int n_in,
                              void* d_out, int out_size, void* d_ws, size_t ws_size,
                              hipStream_t stream) {
    const float4* patches4 = (const float4*)d_in[0];
    const int*    pos_h    = (const int*)d_in[1];
    const int*    pos_w    = (const int*)d_in[2];
    const int*    mask     = (const int*)d_in[3];
    const float*  n_old    = (const float*)d_in[4];
    const float*  mean     = (const float*)d_in[5];
    const float*  m2       = (const float*)d_in[6];
    float4* out4 = (float4*)d_out;

    // workspace: ushort pf16[NTOK] (64 KB) | int cnt[HW] | int list[HW*MAXTOK]
    unsigned short* pf16 = (unsigned short*)d_ws;
    int* cnt  = (int*)(pf16 + NTOK);
    int* list = cnt + HW;

    k_pf<<<NTOK / 256, 256, 0, stream>>>(pos_h, pos_w, mask, pf16, cnt);
    k_fill<<<NTOK / 256, 256, 0, stream>>>(pf16, cnt, list);
    k_cell<<<HW, 256, 0, stream>>>(patches4, pf16, cnt, list,
                                   n_old, mean, m2, out4);
}